// Round 8
// baseline (236.077 us; speedup 1.0000x reference)
//
#include <hip/hip_runtime.h>
#include <cmath>

// Problem constants
#define B_   8
#define N_   4096
#define DIN1 64
#define DHID 128
#define DOUT2 64
#define MAXDEG 256

typedef float f32x2 __attribute__((ext_vector_type(2)));

// ---------------- bf16 helpers -------------------------------------------
__device__ __forceinline__ unsigned pack2bf(float a, float b) {
    unsigned ua = __float_as_uint(a), ub = __float_as_uint(b);
    ua = (ua + 0x7FFFu + ((ua >> 16) & 1u)) >> 16;
    ub = (ub + 0x7FFFu + ((ub >> 16) & 1u)) & 0xFFFF0000u;
    return ua | ub;          // lo half = a, hi half = b
}
// LAZY unpack into a packed float2: hi element keeps low-16 garbage bits
// (<=2^-7 relative mantissa perturbation, exponent untouched). Deterministic;
// identical for q-init and loop -> self score bit-exact.
__device__ __forceinline__ f32x2 lazy2(unsigned u) {
    f32x2 r;
    r.x = __uint_as_float(u << 16);
    r.y = __uint_as_float(u);
    return r;
}

template <int SH>
__device__ __forceinline__ float dpp_shr_add(float p) {
    int t = __builtin_amdgcn_update_dpp(0, __float_as_int(p),
                                        0x110 | SH, 0xF, 0xF, true);
    return p + __int_as_float(t);
}
// Row-sum lands on the TOP lane of each GRPL-lane subgroup.
template <int GRPL>
__device__ __forceinline__ float dpp_reduce(float p) {
    if constexpr (GRPL == 16) p = dpp_shr_add<8>(p);
    p = dpp_shr_add<4>(p);
    p = dpp_shr_add<2>(p);
    p = dpp_shr_add<1>(p);
    return p;   // valid on lane GRPL-1 of each subgroup
}

// ---------------------------------------------------------------------------
// Kernel 1: adjacency -> neighbor lists. Wave per row, ballot compaction.
// ---------------------------------------------------------------------------
__global__ __launch_bounds__(256) void k_build_csr(
    const float* __restrict__ graph, int* __restrict__ cnt, int* __restrict__ idx)
{
    const int wave = threadIdx.x >> 6;
    const int lane = threadIdx.x & 63;
    const int n = blockIdx.x * 4 + wave;
    const unsigned long long below_mask = (1ULL << lane) - 1ULL;

    const float4* __restrict__ row4 = (const float4*)(graph + (size_t)n * N_);
    int* __restrict__ myidx = idx + (size_t)n * MAXDEG;

    int base = 0;
    for (int it = 0; it < N_ / 256; ++it) {
        const int i4 = it * 64 + lane;
        float4 g = row4[i4];
        const int e = 4 * i4;
#pragma unroll
        for (int c = 0; c < 4; ++c) {
            const float gc = (c == 0) ? g.x : (c == 1) ? g.y : (c == 2) ? g.z : g.w;
            const unsigned long long mk = __ballot(gc != 0.0f);
            const int pos = base + __popcll(mk & below_mask);
            if (gc != 0.0f && pos < MAXDEG) myidx[pos] = e + c;
            base += __popcll(mk);
        }
    }
    if (lane == 0) cnt[n] = (base < MAXDEG) ? base : MAXDEG;
}

// ---------------------------------------------------------------------------
// Kernel 2a: linear1 with DUAL WRITE: fp32 h1 (exact) + bf16 h1b. [proven]
// ---------------------------------------------------------------------------
__global__ __launch_bounds__(256) void k_linear1(
    const float* __restrict__ x, const float* __restrict__ W,
    float* __restrict__ out, void* __restrict__ outb)
{
    constexpr int DIN = DIN1, DOUT = DHID;
    constexpr int CG = DOUT / 4;      // 32
    constexpr int RG = 256 / CG;      // 8
    constexpr int TR = 32 / RG;       // 4

    __shared__ float sWt[DIN][DOUT + 4];

    const int t = threadIdx.x;
    const float4* W4 = (const float4*)W;
    for (int i = t; i < DOUT * (DIN / 4); i += 256) {
        int kk = i / (DIN / 4);
        int d4 = i % (DIN / 4);
        float4 w = W4[i];
        sWt[4 * d4 + 0][kk] = w.x;
        sWt[4 * d4 + 1][kk] = w.y;
        sWt[4 * d4 + 2][kk] = w.z;
        sWt[4 * d4 + 3][kk] = w.w;
    }
    __syncthreads();

    const int rg = t / CG;
    const int c  = t % CG;
    const int base = blockIdx.x * 32;
    const float4* x4 = (const float4*)x;

    float acc[TR][4];
#pragma unroll
    for (int i = 0; i < TR; ++i)
#pragma unroll
        for (int j = 0; j < 4; ++j) acc[i][j] = 0.0f;

    for (int d4 = 0; d4 < DIN / 4; ++d4) {
        float4 xf[TR];
#pragma unroll
        for (int i = 0; i < TR; ++i)
            xf[i] = x4[(size_t)(base + rg * TR + i) * (DIN / 4) + d4];
        float4 wf[4];
#pragma unroll
        for (int dd = 0; dd < 4; ++dd)
            wf[dd] = *(const float4*)&sWt[4 * d4 + dd][4 * c];
#pragma unroll
        for (int i = 0; i < TR; ++i) {
            acc[i][0] += xf[i].x * wf[0].x + xf[i].y * wf[1].x + xf[i].z * wf[2].x + xf[i].w * wf[3].x;
            acc[i][1] += xf[i].x * wf[0].y + xf[i].y * wf[1].y + xf[i].z * wf[2].y + xf[i].w * wf[3].y;
            acc[i][2] += xf[i].x * wf[0].z + xf[i].y * wf[1].z + xf[i].z * wf[2].z + xf[i].w * wf[3].z;
            acc[i][3] += xf[i].x * wf[0].w + xf[i].y * wf[1].w + xf[i].z * wf[2].w + xf[i].w * wf[3].w;
        }
    }

#pragma unroll
    for (int i = 0; i < TR; ++i) {
        const size_t row = (size_t)(base + rg * TR + i);
        float4 o = {acc[i][0], acc[i][1], acc[i][2], acc[i][3]};
        ((float4*)out)[row * CG + c] = o;
        uint2 ob = {pack2bf(o.x, o.y), pack2bf(o.z, o.w)};
        *(uint2*)((char*)outb + row * (DOUT * 2) + c * 8) = ob;
    }
}

// ---------------------------------------------------------------------------
// Kernel 2b: plain fp32 register-tiled linear (layer 2). [proven]
// ---------------------------------------------------------------------------
template <int DIN, int DOUT>
__global__ __launch_bounds__(256) void k_linear(
    const float* __restrict__ x, const float* __restrict__ W,
    float* __restrict__ out)
{
    constexpr int CG = DOUT / 4;
    constexpr int RG = 256 / CG;
    constexpr int TR = 32 / RG;

    __shared__ float sWt[DIN][DOUT + 4];

    const int t = threadIdx.x;
    const float4* W4 = (const float4*)W;
    for (int i = t; i < DOUT * (DIN / 4); i += 256) {
        int kk = i / (DIN / 4);
        int d4 = i % (DIN / 4);
        float4 w = W4[i];
        sWt[4 * d4 + 0][kk] = w.x;
        sWt[4 * d4 + 1][kk] = w.y;
        sWt[4 * d4 + 2][kk] = w.z;
        sWt[4 * d4 + 3][kk] = w.w;
    }
    __syncthreads();

    const int rg = t / CG;
    const int c  = t % CG;
    const int base = blockIdx.x * 32;
    const float4* x4 = (const float4*)x;

    float acc[TR][4];
#pragma unroll
    for (int i = 0; i < TR; ++i)
#pragma unroll
        for (int j = 0; j < 4; ++j) acc[i][j] = 0.0f;

    for (int d4 = 0; d4 < DIN / 4; ++d4) {
        float4 xf[TR];
#pragma unroll
        for (int i = 0; i < TR; ++i)
            xf[i] = x4[(size_t)(base + rg * TR + i) * (DIN / 4) + d4];
        float4 wf[4];
#pragma unroll
        for (int dd = 0; dd < 4; ++dd)
            wf[dd] = *(const float4*)&sWt[4 * d4 + dd][4 * c];
#pragma unroll
        for (int i = 0; i < TR; ++i) {
            acc[i][0] += xf[i].x * wf[0].x + xf[i].y * wf[1].x + xf[i].z * wf[2].x + xf[i].w * wf[3].x;
            acc[i][1] += xf[i].x * wf[0].y + xf[i].y * wf[1].y + xf[i].z * wf[2].y + xf[i].w * wf[3].y;
            acc[i][2] += xf[i].x * wf[0].z + xf[i].y * wf[1].z + xf[i].z * wf[2].z + xf[i].w * wf[3].z;
            acc[i][3] += xf[i].x * wf[0].w + xf[i].y * wf[1].w + xf[i].z * wf[2].w + xf[i].w * wf[3].w;
        }
    }

#pragma unroll
    for (int i = 0; i < TR; ++i) {
        float4 o = {acc[i][0], acc[i][1], acc[i][2], acc[i][3]};
        ((float4*)out)[(size_t)(base + rg * TR + i) * CG + c] = o;
    }
}

// ---------------------------------------------------------------------------
// Kernel 3a: attn layer-1, GS=4 lazy-bf16, DUAL-BATCH (b and b+4 per wave).
// The neighbor offsets, loop control, LDS reads, and voffset math are
// batch-invariant -> amortized over 2 batches; the two dpp-reduce chains
// are independent -> overlap (the serial reduce was the latency critical
// path). Dot uses ext_vector f32x2 -> guaranteed v_pk_fma_f32. Per-batch
// math is the exact R7 sequence: lazy unpack, fixed-order dot (init and
// loop share it -> self score bit-exact -> one-hot exact), screen at
// m-100, fp32 reload on taken, torch masked_fill(s==0) semantics, fp32
// all-masked fallback. VGPR ~75: static cap >=7 waves/SIMD (> achieved
// ~4.6) so occupancy headroom preserved.
// ---------------------------------------------------------------------------
__global__ __launch_bounds__(256) void k_attn1(
    const void* __restrict__ h16, const float* __restrict__ h32,
    const int* __restrict__ cnt, const int* __restrict__ idx,
    const float* __restrict__ bias, float* __restrict__ out)
{
    constexpr int RBb = DHID * 2;   // bf16 row bytes (256)
    constexpr int RBf = DHID * 4;   // fp32 row bytes (512)
    constexpr int GS  = 4;          // 4 streams of 16 lanes
    constexpr unsigned long long TM = 0x8000800080008000ULL;

    const int bid  = blockIdx.x;
    const int bA   = bid & 3;                    // batches bA and bA+4
    const int wave = threadIdx.x >> 6;
    const int lane = threadIdx.x & 63;
    const int n    = (bid >> 2) * 4 + wave;      // one query (x2 batches)/wave
    const int grp  = lane >> 4;
    const int gl   = lane & 15;
    const int gtop = lane | 15;

    __shared__ int s_off[4][MAXDEG + 48];        // bf16 byte offsets (shared)

    const int k = cnt[n];
    const int* __restrict__ myidx = idx + (size_t)n * MAXDEG;
    for (int j = lane; j < k; j += 64) s_off[wave][j] = myidx[j] * RBb;
    for (int z = k + lane; z < k + 48; z += 64) s_off[wave][z] = 0;

    const char* __restrict__ hbA = (const char*)h16 + (size_t)bA * N_ * RBb;
    const char* __restrict__ hbB = hbA + (size_t)4 * N_ * RBb;
    const char* __restrict__ hfA = (const char*)h32 + (size_t)bA * N_ * RBf;
    const char* __restrict__ hfB = hfA + (size_t)4 * N_ * RBf;
    const int lb = gl * 16;                      // lane's bf16 byte slot (8 dims)

    // q fragments (8 dims/lane) for both batches
    f32x2 qA[4], qB[4];
    {
        const uint4 ua = *(const uint4*)(hbA + (size_t)n * RBb + lb);
        qA[0] = lazy2(ua.x); qA[1] = lazy2(ua.y);
        qA[2] = lazy2(ua.z); qA[3] = lazy2(ua.w);
        const uint4 ub = *(const uint4*)(hbB + (size_t)n * RBb + lb);
        qB[0] = lazy2(ub.x); qB[1] = lazy2(ub.y);
        qB[2] = lazy2(ub.z); qB[3] = lazy2(ub.w);
    }

    // fixed-order packed dot; identical sequence for self-init and loop
    auto dot8 = [](const f32x2* q, const f32x2* c) -> float {
        f32x2 pa = q[0] * c[0];
        f32x2 pb = q[1] * c[1];
        pa += q[2] * c[2];
        pb += q[3] * c[3];
        f32x2 t = pa + pb;
        return t.x + t.y;
    };

    float mA, mB;
    {
        float pA = dot8(qA, qA);
        float pB = dot8(qB, qB);
        pA = dpp_reduce<16>(pA);
        pB = dpp_reduce<16>(pB);
        const float ba = __shfl(pA, gtop, 64);
        const float bb = __shfl(pB, gtop, 64);
        mA = (ba != 0.0f) ? ba : -INFINITY;
        mB = (bb != 0.0f) ? bb : -INFINITY;
    }
    float mtA = mA - 100.0f, mtB = mB - 100.0f;
    float sA = 0.0f, sB = 0.0f;
    float aA[8], aB[8];
#pragma unroll
    for (int i = 0; i < 8; ++i) { aA[i] = 0.0f; aB[i] = 0.0f; }

    // taken path accumulates from the FP32 row (off = bf16 offset; x2 for fp32)
    auto take = [&](float pb, int off, const char* hf,
                    float& m, float& mt, float& s, float* acc) {
        const bool valid = (pb != 0.0f);          // dot==0 => masked (torch)
        const float pm   = valid ? pb : m;
        const float newm = fmaxf(m, pm);
        const float f = (m == newm) ? 1.0f : __expf(m - newm);
        const float e = valid ? __expf(pb - newm) : 0.0f;
        s = s * f + e;
        const float4* fr = (const float4*)(hf + 2 * (size_t)off) + 2 * gl;
        const float4 lo = fr[0], hi = fr[1];
        const float f8[8] = {lo.x, lo.y, lo.z, lo.w, hi.x, hi.y, hi.z, hi.w};
#pragma unroll
        for (int i = 0; i < 8; ++i) acc[i] = acc[i] * f + e * f8[i];
        m = newm;
        mt = m - 100.0f;
    };

    auto proc2 = [&](const uint4 ca, const uint4 cb, int off) {
        f32x2 xa[4] = {lazy2(ca.x), lazy2(ca.y), lazy2(ca.z), lazy2(ca.w)};
        float pA = dot8(qA, xa);
        f32x2 xb[4] = {lazy2(cb.x), lazy2(cb.y), lazy2(cb.z), lazy2(cb.w)};
        float pB = dot8(qB, xb);
        pA = dpp_reduce<16>(pA);
        pB = dpp_reduce<16>(pB);
        const unsigned long long tA = __ballot(pA > mtA) & TM;
        const unsigned long long tB = __ballot(pB > mtB) & TM;
        if (__builtin_expect((tA | tB) != 0ULL, 0)) {
            if (tA) take(__shfl(pA, gtop, 64), off, hfA, mA, mtA, sA, aA);
            if (tB) take(__shfl(pB, gtop, 64), off, hfB, mB, mtB, sB, aB);
        }
    };

    // depth-2 data + depth-4 offset pipeline (proven rotation), dual loads
    {
        uint4 a0, a1, a2, b0, b1, b2;
        int u0, u1, u2, f0, f1, f2;
        f0 = s_off[wave][grp + 2 * GS];
        f1 = s_off[wave][grp + 3 * GS];
        u0 = s_off[wave][grp];
        a0 = *(const uint4*)(hbA + u0 + lb);
        b0 = *(const uint4*)(hbB + u0 + lb);
        u1 = s_off[wave][grp + GS];
        a1 = *(const uint4*)(hbA + u1 + lb);
        b1 = *(const uint4*)(hbB + u1 + lb);
        int j = grp;
        while (j < k) {
            f2 = s_off[wave][j + 4 * GS];
            u2 = f0;
            a2 = *(const uint4*)(hbA + u2 + lb);
            b2 = *(const uint4*)(hbB + u2 + lb);
            proc2(a0, b0, u0);
            j += GS; if (j >= k) break;
            f0 = s_off[wave][j + 4 * GS];
            u0 = f1;
            a0 = *(const uint4*)(hbA + u0 + lb);
            b0 = *(const uint4*)(hbB + u0 + lb);
            proc2(a1, b1, u1);
            j += GS; if (j >= k) break;
            f1 = f2;
            u1 = f2;   // rotate: consume prefetched f2
            f1 = s_off[wave][j + 4 * GS];
            a1 = *(const uint4*)(hbA + u1 + lb);
            b1 = *(const uint4*)(hbB + u1 + lb);
            proc2(a2, b2, u2);
            j += GS;
        }
    }

    // merge the 4 subgroup states (xor 16, 32) for both batches
#pragma unroll
    for (int mask = 16; mask <= 32; mask <<= 1) {
        const float m2A = __shfl_xor(mA, mask, 64);
        const float s2A = __shfl_xor(sA, mask, 64);
        const float m2B = __shfl_xor(mB, mask, 64);
        const float s2B = __shfl_xor(sB, mask, 64);
        float xA[8], xB[8];
#pragma unroll
        for (int i = 0; i < 8; ++i) {
            xA[i] = __shfl_xor(aA[i], mask, 64);
            xB[i] = __shfl_xor(aB[i], mask, 64);
        }
        {
            const float mm = fmaxf(mA, m2A);
            const float f1 = (mA  == mm) ? 1.0f : __expf(mA  - mm);
            const float f2 = (m2A == mm) ? 1.0f : __expf(m2A - mm);
            sA = sA * f1 + s2A * f2;
#pragma unroll
            for (int i = 0; i < 8; ++i) aA[i] = aA[i] * f1 + xA[i] * f2;
            mA = mm;
        }
        {
            const float mm = fmaxf(mB, m2B);
            const float f1 = (mB  == mm) ? 1.0f : __expf(mB  - mm);
            const float f2 = (m2B == mm) ? 1.0f : __expf(m2B - mm);
            sB = sB * f1 + s2B * f2;
#pragma unroll
            for (int i = 0; i < 8; ++i) aB[i] = aB[i] * f1 + xB[i] * f2;
            mB = mm;
        }
    }

    // epilogue: grp 0 writes batch A, grp 1 writes batch B (parallel)
    auto writerow = [&](int bb, const float* acc, float s) {
        const float4* bias4 = (const float4*)bias;
        const float4 b0 = bias4[2 * gl], b1 = bias4[2 * gl + 1];
        const float bi[8] = {b0.x, b0.y, b0.z, b0.w, b1.x, b1.y, b1.z, b1.w};
        const float inv = 1.0f / s;
        float4 lo, hi;
        lo.x = fmaxf(acc[0] * inv + bi[0], 0.0f);
        lo.y = fmaxf(acc[1] * inv + bi[1], 0.0f);
        lo.z = fmaxf(acc[2] * inv + bi[2], 0.0f);
        lo.w = fmaxf(acc[3] * inv + bi[3], 0.0f);
        hi.x = fmaxf(acc[4] * inv + bi[4], 0.0f);
        hi.y = fmaxf(acc[5] * inv + bi[5], 0.0f);
        hi.z = fmaxf(acc[6] * inv + bi[6], 0.0f);
        hi.w = fmaxf(acc[7] * inv + bi[7], 0.0f);
        float4* orow = (float4*)out + ((size_t)bb * N_ + n) * (DHID / 4) + 2 * gl;
        orow[0] = lo;
        orow[1] = hi;
    };
    // RARE (all masked): uniform softmax -> column mean of fp32 h[b]
    auto fallback = [&](int bb, const char* hf) {
        const float4* hf4 = (const float4*)hf;
        const int sl = lane % 32;
        const int rs = lane / 32;
        float4 a = {0.0f, 0.0f, 0.0f, 0.0f};
        for (int row = rs; row < N_; row += 2) {
            float4 v = hf4[(size_t)row * 32 + sl];
            a.x += v.x; a.y += v.y; a.z += v.z; a.w += v.w;
        }
        a.x += __shfl_xor(a.x, 32, 64);
        a.y += __shfl_xor(a.y, 32, 64);
        a.z += __shfl_xor(a.z, 32, 64);
        a.w += __shfl_xor(a.w, 32, 64);
        if (lane < 32) {
            constexpr float invN = 1.0f / (float)N_;
            const float4 bi = ((const float4*)bias)[sl];
            float4 o;
            o.x = fmaxf(a.x * invN + bi.x, 0.0f);
            o.y = fmaxf(a.y * invN + bi.y, 0.0f);
            o.z = fmaxf(a.z * invN + bi.z, 0.0f);
            o.w = fmaxf(a.w * invN + bi.w, 0.0f);
            ((float4*)out)[((size_t)bb * N_ + n) * 32 + sl] = o;
        }
    };

    if (sA > 0.0f) { if (grp == 0) writerow(bA, aA, sA); }
    if (sB > 0.0f) { if (grp == 1) writerow(bA + 4, aB, sB); }
    if (sA <= 0.0f) fallback(bA, hfA);
    if (sB <= 0.0f) fallback(bA + 4, hfB);
}

// ---------------------------------------------------------------------------
// Kernel 3b: attn layer-2, fp32, GS=4 (R7-proven). Dot f32x2-ified: the new
// pairing {x,y}+fma{z,w} is BIT-IDENTICAL to the R7 two-chain scalar order.
// ---------------------------------------------------------------------------
__global__ __launch_bounds__(256) void k_attn2(
    const float* __restrict__ h, const int* __restrict__ cnt,
    const int* __restrict__ idx, const float* __restrict__ bias,
    float* __restrict__ out)
{
    constexpr int D  = DOUT2;
    constexpr int V  = D / 4;                    // 16
    constexpr int GS = 4;                        // 4 streams of 16 lanes
    constexpr int RB = D * 4;                    // 256

    const int bid  = blockIdx.x;
    const int b    = bid & 7;
    const int wave = threadIdx.x >> 6;
    const int lane = threadIdx.x & 63;
    const int n    = (bid >> 3) * 4 + wave;
    const int grp  = lane >> 4;
    const int gl   = lane & 15;
    const int gtop = lane | 15;

    __shared__ int s_off[4][MAXDEG + 48];

    const int k = cnt[n];
    const int* __restrict__ myidx = idx + (size_t)n * MAXDEG;
    for (int j = lane; j < k; j += 64) s_off[wave][j] = myidx[j] * RB;
    for (int z = k + lane; z < k + 48; z += 64) s_off[wave][z] = 0;

    const char* __restrict__ hb = (const char*)h + (size_t)b * N_ * RB;
    const int lb = gl * 16;                      // dims [4gl, 4gl+4)

    float4 qf;
    qf = *(const float4*)(hb + (size_t)n * RB + lb);
    f32x2 q01, q23;
    q01.x = qf.x; q01.y = qf.y;
    q23.x = qf.z; q23.y = qf.w;

    // bit-identical to R7's two-chain order:
    // t.x = fma(qz,cz, qx*cx), t.y = fma(qw,cw, qy*cy); return t.x+t.y
    auto dotc = [&](const float4 c) -> float {
        f32x2 c01, c23;
        c01.x = c.x; c01.y = c.y;
        c23.x = c.z; c23.y = c.w;
        f32x2 t = q01 * c01;
        t += q23 * c23;
        return t.x + t.y;
    };

    float m;
    {
        float p = dotc(qf);
        p = dpp_reduce<16>(p);
        const float pb = __shfl(p, gtop, 64);
        m = (pb != 0.0f) ? pb : -INFINITY;
    }
    float mt = m - 100.0f;
    float s = 0.0f;
    float4 acc = {0.0f, 0.0f, 0.0f, 0.0f};

    auto process = [&](const float4 cur) {
        float p = dotc(cur);
        p = dpp_reduce<16>(p);
        if (__builtin_expect((__ballot(p > mt) & 0x8000800080008000ULL) != 0ULL, 0)) {
            const float pb = __shfl(p, gtop, 64);
            const bool valid = (pb != 0.0f);
            const float pm   = valid ? pb : m;
            const float newm = fmaxf(m, pm);
            const float f = (m == newm) ? 1.0f : __expf(m - newm);
            const float e = valid ? __expf(pb - newm) : 0.0f;
            s = s * f + e;
            acc.x = acc.x * f + e * cur.x;
            acc.y = acc.y * f + e * cur.y;
            acc.z = acc.z * f + e * cur.z;
            acc.w = acc.w * f + e * cur.w;
            m = newm;
            mt = m - 100.0f;
        }
    };

    // depth-2 data + depth-4 offset pipeline
    {
        float4 r0, r1, r2;
        int oA, oB, oC;
        oA = s_off[wave][grp + 2 * GS];
        oB = s_off[wave][grp + 3 * GS];
        r0 = *(const float4*)(hb + s_off[wave][grp] + lb);
        r1 = *(const float4*)(hb + s_off[wave][grp + GS] + lb);
        int j = grp;
        while (j < k) {
            oC = s_off[wave][j + 4 * GS];
            r2 = *(const float4*)(hb + oA + lb);
            process(r0);
            j += GS; if (j >= k) break;
            oA = s_off[wave][j + 4 * GS];
            r0 = *(const float4*)(hb + oB + lb);
            process(r1);
            j += GS; if (j >= k) break;
            oB = s_off[wave][j + 4 * GS];
            r1 = *(const float4*)(hb + oC + lb);
            process(r2);
            j += GS;
        }
    }

    // merge the 4 subgroup states (xor 16, 32)
#pragma unroll
    for (int mask = 16; mask <= 32; mask <<= 1) {
        const float m2 = __shfl_xor(m, mask, 64);
        const float s2 = __shfl_xor(s, mask, 64);
        float4 a2;
        a2.x = __shfl_xor(acc.x, mask, 64);
        a2.y = __shfl_xor(acc.y, mask, 64);
        a2.z = __shfl_xor(acc.z, mask, 64);
        a2.w = __shfl_xor(acc.w, mask, 64);
        const float mm = fmaxf(m, m2);
        const float f1 = (m  == mm) ? 1.0f : __expf(m  - mm);
        const float f2 = (m2 == mm) ? 1.0f : __expf(m2 - mm);
        s = s * f1 + s2 * f2;
        acc.x = acc.x * f1 + a2.x * f2;
        acc.y = acc.y * f1 + a2.y * f2;
        acc.z = acc.z * f1 + a2.z * f2;
        acc.w = acc.w * f1 + a2.w * f2;
        m = mm;
    }

    if (s > 0.0f) {
        if (grp == 0) {
            const float4 bi = ((const float4*)bias)[gl];
            const float inv = 1.0f / s;
            float4 o;
            o.x = acc.x * inv + bi.x;
            o.y = acc.y * inv + bi.y;
            o.z = acc.z * inv + bi.z;
            o.w = acc.w * inv + bi.w;
            ((float4*)out)[((size_t)b * N_ + n) * V + gl] = o;
        }
    } else {
        const float4* hb4 = (const float4*)hb;
        const int sl = lane % V;
        const int rs = lane / V;
        float4 a = {0.0f, 0.0f, 0.0f, 0.0f};
        for (int row = rs; row < N_; row += 4) {
            float4 v = hb4[(size_t)row * V + sl];
            a.x += v.x; a.y += v.y; a.z += v.z; a.w += v.w;
        }
#pragma unroll
        for (int mask = 16; mask <= 32; mask <<= 1) {
            a.x += __shfl_xor(a.x, mask, 64);
            a.y += __shfl_xor(a.y, mask, 64);
            a.z += __shfl_xor(a.z, mask, 64);
            a.w += __shfl_xor(a.w, mask, 64);
        }
        if (lane < V) {
            constexpr float invN = 1.0f / (float)N_;
            const float4 bi = ((const float4*)bias)[sl];
            float4 o;
            o.x = a.x * invN + bi.x;
            o.y = a.y * invN + bi.y;
            o.z = a.z * invN + bi.z;
            o.w = a.w * invN + bi.w;
            ((float4*)out)[((size_t)b * N_ + n) * V + sl] = o;
        }
    }
}

// ---------------------------------------------------------------------------
// Launch
// ---------------------------------------------------------------------------
extern "C" void kernel_launch(void* const* d_in, const int* in_sizes, int n_in,
                              void* d_out, int out_size, void* d_ws, size_t ws_size,
                              hipStream_t stream) {
    (void)in_sizes; (void)n_in; (void)out_size; (void)ws_size;

    const float* flow_x = (const float*)d_in[0];
    const float* graph  = (const float*)d_in[1];
    const float* W1     = (const float*)d_in[2];
    const float* b1     = (const float*)d_in[3];
    const float* W2     = (const float*)d_in[4];
    const float* b2     = (const float*)d_in[5];
    float* out = (float*)d_out;

    char* p = (char*)d_ws;
    auto carve = [&](size_t bytes) -> void* {
        void* r = (void*)p;
        p += (bytes + 255) & ~(size_t)255;
        return r;
    };
    int*   nbr_cnt = (int*)carve((size_t)N_ * sizeof(int));
    int*   nbr_idx = (int*)carve((size_t)N_ * MAXDEG * sizeof(int));
    float* h1      = (float*)carve((size_t)B_ * N_ * DHID * sizeof(float));
    void*  h1b     = carve((size_t)B_ * N_ * DHID * 2);   // bf16 copy
    float* x2      = (float*)carve((size_t)B_ * N_ * DHID * sizeof(float));
    float* h2      = (float*)carve((size_t)B_ * N_ * DOUT2 * sizeof(float));

    // 1. adjacency -> neighbor lists
    k_build_csr<<<N_ / 4, 256, 0, stream>>>(graph, nbr_cnt, nbr_idx);

    // 2. layer 1 linear: fp32 h1 + bf16 h1b (dual write)
    k_linear1<<<(B_ * N_) / 32, 256, 0, stream>>>(flow_x, W1, h1, h1b);

    // 3. layer 1 attention: dual-batch (b, b+4) per wave -> x2
    k_attn1<<<N_ * B_ / 8, 256, 0, stream>>>(h1b, h1, nbr_cnt, nbr_idx, b1, x2);

    // 4. layer 2 linear (fp32)
    k_linear<DHID, DOUT2><<<(B_ * N_) / 32, 256, 0, stream>>>(x2, W2, h2);

    // 5. layer 2 attention (fp32, GS=4) -> d_out  ([B,N,1,64] flat)
    k_attn2<<<N_ * B_ / 4, 256, 0, stream>>>(h2, nbr_cnt, nbr_idx, b2, out);
}